// Round 11
// baseline (45.876 us; speedup 1.0000x reference)
//
#include <hip/hip_runtime.h>

// MSCA fused multi-scale depthwise conv chain. x:[8,256,64,64] f32 -> 3 outputs.
//
// R10 = R9 phase bodies, but each block processes TWO planes sequentially with
// cross-plane prefetch: plane1's x is global-loaded into regs at start of P4
// (plane0) and committed to LDS during P5 (plane0), hiding the ~900cy HBM load
// behind compute. LDS regions (both 68x68) swap roles per plane:
//   plane0: RA = X->Y0->Y2, RB = ATT_T->Y1 ; plane1: swapped.
// Grid 1024 (2 planes/block). 512 thr, strips of 8, DPP halos (hoisted+select),
// transpose involution swizzle (R7-proven). 10 barriers / 2 planes.
//
//   scatter:  buf[(8*lane8+e)*68 + (maj ^ (lane8<<3))]
//   strip rd: buf[maj*68 + ((lane8 ^ ((maj>>3)&7))<<3) + e]   (2x b128)

#define RG_W 4624                  // 68*68 (both regions X-capable)
#define LDS_WORDS (2 * RG_W)       // 9248 words = 36992 B

__device__ __forceinline__ float dppsr1(float v) {   // lane i <- i-1 (16-lane rows)
    return __int_as_float(__builtin_amdgcn_update_dpp(
        0, __float_as_int(v), 0x111, 0xF, 0xF, false));
}
__device__ __forceinline__ float dppsr2(float v) {   // lane i <- i-2
    return __int_as_float(__builtin_amdgcn_update_dpp(
        0, __float_as_int(v), 0x112, 0xF, 0xF, false));
}
__device__ __forceinline__ float dppsl1(float v) {   // lane i <- i+1
    return __int_as_float(__builtin_amdgcn_update_dpp(
        0, __float_as_int(v), 0x101, 0xF, 0xF, false));
}
__device__ __forceinline__ float dppsl2(float v) {   // lane i <- i+2
    return __int_as_float(__builtin_amdgcn_update_dpp(
        0, __float_as_int(v), 0x102, 0xF, 0xF, false));
}
__device__ __forceinline__ void ld8(const float* p, float* d) {
    float4 a = *(const float4*)p, b = *(const float4*)(p + 4);
    d[0]=a.x; d[1]=a.y; d[2]=a.z; d[3]=a.w; d[4]=b.x; d[5]=b.y; d[6]=b.z; d[7]=b.w;
}
__device__ __forceinline__ void st8(float* p, const float* d) {
    float4 a, b;
    a.x=d[0]; a.y=d[1]; a.z=d[2]; a.w=d[3]; b.x=d[4]; b.y=d[5]; b.z=d[6]; b.w=d[7];
    *(float4*)p = a; *(float4*)(p + 4) = b;
}

// zero X halos + write this thread's 8-col strip of row maj (image -> buf+2,+2)
__device__ __forceinline__ void commit_x(float* RX, const float* xr,
                                         int t, int maj, int j0) {
    if (t < 136) { RX[t] = 0.f; RX[t + 4488] = 0.f; }        // rows 0,1,66,67
    if (t < 256) {                                            // side cols rows 2..65
        int rr = 2 + (t >> 2), cc = t & 3;
        RX[rr * 68 + (cc < 2 ? cc : cc + 64)] = 0.f;
    }
    float* row = &RX[(maj + 2) * 68 + j0 + 2];
    float2 p;
    p.x = xr[0]; p.y = xr[1]; ((float2*)row)[0] = p;
    p.x = xr[2]; p.y = xr[3]; ((float2*)row)[1] = p;
    p.x = xr[4]; p.y = xr[5]; ((float2*)row)[2] = p;
    p.x = xr[6]; p.y = xr[7]; ((float2*)row)[3] = p;
}

// Accumulate window part: src[i] at window position W0+i (N elems), static idx.
template<int K, int W0, int N>
__device__ __forceinline__ void cpart(const float* __restrict__ wt,
                                      const float* s, float* acc) {
    #pragma unroll
    for (int v = 0; v < K; v++) {
        #pragma unroll
        for (int j = 0; j < 8; j++) {
            const int p = j + v - W0;
            if (p >= 0 && p < N) acc[j] += wt[v] * s[p];
        }
    }
}

// Strip conv, K=2H+1 taps, H<=8: halo from lane+-1 (DPP hoisted, select after).
template<int H>
__device__ __forceinline__ void sconv(const float* __restrict__ wt, float bb,
                                      const float* a, bool pm, bool np, float* acc) {
    constexpr int K = 2 * H + 1;
    float pv[H], nv[H];
    #pragma unroll
    for (int i = 0; i < H; i++) pv[i] = dppsr1(a[8 - H + i]);
    #pragma unroll
    for (int i = 0; i < H; i++) nv[i] = dppsl1(a[i]);
    #pragma unroll
    for (int i = 0; i < H; i++) pv[i] = pm ? pv[i] : 0.f;
    #pragma unroll
    for (int i = 0; i < H; i++) nv[i] = np ? nv[i] : 0.f;
    #pragma unroll
    for (int j = 0; j < 8; j++) acc[j] = bb;
    cpart<K, 0, H>(wt, pv, acc);
    cpart<K, H, 8>(wt, a, acc);
    cpart<K, H + 8, H>(wt, nv, acc);
}

// 21-tap strip conv (H=10): halo spans lane+-1 (8) and lane+-2 (2).
__device__ __forceinline__ void sconv21(const float* __restrict__ wt, float bb,
                                        const float* a, bool pm, bool pm2,
                                        bool np, bool np2, float* acc) {
    #pragma unroll
    for (int j = 0; j < 8; j++) acc[j] = bb;
    {
        float q[2];
        q[0] = dppsr2(a[6]); q[1] = dppsr2(a[7]);
        q[0] = pm2 ? q[0] : 0.f; q[1] = pm2 ? q[1] : 0.f;
        cpart<21, 0, 2>(wt, q, acc);
    }
    {
        float pv[8];
        #pragma unroll
        for (int i = 0; i < 8; i++) pv[i] = dppsr1(a[i]);
        #pragma unroll
        for (int i = 0; i < 8; i++) pv[i] = pm ? pv[i] : 0.f;
        cpart<21, 2, 8>(wt, pv, acc);
    }
    cpart<21, 10, 8>(wt, a, acc);
    {
        float nv[8];
        #pragma unroll
        for (int i = 0; i < 8; i++) nv[i] = dppsl1(a[i]);
        #pragma unroll
        for (int i = 0; i < 8; i++) nv[i] = np ? nv[i] : 0.f;
        cpart<21, 18, 8>(wt, nv, acc);
    }
    {
        float q[2];
        q[0] = dppsl2(a[0]); q[1] = dppsl2(a[1]);
        q[0] = np2 ? q[0] : 0.f; q[1] = np2 ? q[1] : 0.f;
        cpart<21, 26, 2>(wt, q, acc);
    }
}

__global__ __launch_bounds__(512, 4)
void msca_fused(const float* __restrict__ x,
                const float* __restrict__ w0,   const float* __restrict__ b0,
                const float* __restrict__ w0_1, const float* __restrict__ b0_1,
                const float* __restrict__ w0_2, const float* __restrict__ b0_2,
                const float* __restrict__ w1_1, const float* __restrict__ b1_1,
                const float* __restrict__ w1_2, const float* __restrict__ b1_2,
                const float* __restrict__ w2_1, const float* __restrict__ b2_1,
                const float* __restrict__ w2_2, const float* __restrict__ b2_2,
                float* __restrict__ out)
{
    __shared__ __align__(16) float lds[LDS_WORDS];
    float* RA = lds;
    float* RB = lds + RG_W;

    const int t     = threadIdx.x;     // 0..511
    const int maj   = t >> 3;          // X: image row ; T: image col
    const int lane8 = t & 7;
    const int j0    = lane8 << 3;

    const bool pm  = lane8 >= 1, np  = lane8 <= 6;
    const bool pm2 = lane8 >= 2, np2 = lane8 <= 5;

    const int scat = maj ^ (lane8 << 3);                           // scatter minor
    const int rdb  = maj * 68 + ((lane8 ^ ((maj >> 3) & 7)) << 3); // strip read base

    const int pl0 = blockIdx.x * 2;
    const float* xg1 = x + (size_t)(pl0 + 1) * 4096;

    // ---- plane0 stage0: load + commit x ----
    {
        float xr[8];
        ld8(&x[(size_t)pl0 * 4096 + maj * 64 + j0], xr);
        commit_x(RA, xr, t, maj, j0);
    }
    __syncthreads();   // B1 (plane0 X ready)

    float xrN[8];      // plane1 prefetch (loaded in P4 of plane0)

    #pragma unroll
    for (int p = 0; p < 2; p++) {
        float* RX = p ? RB : RA;   // X -> Y0 -> Y2
        float* RT = p ? RA : RB;   // ATT_T -> Y1
        const int ch = (pl0 + p) & 255;
        float* o0 = out + (size_t)(pl0 + p) * 4096;
        float* o1 = o0 + 8388608;
        float* o2 = o1 + 8388608;

        // ---- P1: attn = conv5x5(x)+b0 (rows from RX); scatter ATT_T -> RT ----
        float attn[8];
        {
            const float bb = b0[ch];
            #pragma unroll
            for (int j = 0; j < 8; j++) attn[j] = bb;
            const float* w0p = w0 + ch * 25;
            #pragma unroll
            for (int dr = 0; dr < 5; dr++) {
                float wnd[12];                      // image cols j0-2 .. j0+9
                const float* rowp = &RX[(maj + dr) * 68 + j0];
                float4 qa = *(const float4*)rowp;
                float4 qb = *(const float4*)(rowp + 4);
                float4 qc = *(const float4*)(rowp + 8);
                wnd[0]=qa.x; wnd[1]=qa.y; wnd[2]=qa.z;  wnd[3]=qa.w;
                wnd[4]=qb.x; wnd[5]=qb.y; wnd[6]=qb.z;  wnd[7]=qb.w;
                wnd[8]=qc.x; wnd[9]=qc.y; wnd[10]=qc.z; wnd[11]=qc.w;
                #pragma unroll
                for (int v = 0; v < 5; v++) {
                    const float ww = w0p[dr * 5 + v];
                    #pragma unroll
                    for (int j = 0; j < 8; j++) attn[j] += ww * wnd[j + v];
                }
            }
            #pragma unroll
            for (int e = 0; e < 8; e++) RT[(j0 + e) * 68 + scat] = attn[e];
        }
        __syncthreads();   // (ATT_T ready; X reads done)

        // ---- P2: a0x; read attn T-strip; a0y; scatter Y0 -> RX ----
        float a0x[8];
        sconv<3>(w0_1 + ch * 7, b0_1[ch], attn, pm, np, a0x);
        float stv[8];
        ld8(&RT[rdb], stv);
        float aty0[8];
        sconv<3>(w0_2 + ch * 7, b0_2[ch], stv, pm, np, aty0);
        #pragma unroll
        for (int d = 0; d < 8; d++) RX[(j0 + d) * 68 + scat] = aty0[d];   // Y0
        __syncthreads();   // (Y0 ready; ATT_T reads done)

        // ---- P3: prod0 = a0x*Y0row; a1x; a1y; scatter Y1 -> RT ----
        float prod0[8];
        {
            float y0r[8];
            ld8(&RX[rdb], y0r);
            #pragma unroll
            for (int j = 0; j < 8; j++) prod0[j] = a0x[j] * y0r[j];
        }
        float a1x[8];
        sconv<5>(w1_1 + ch * 11, b1_1[ch], a0x, pm, np, a1x);
        float aty1[8];
        sconv<5>(w1_2 + ch * 11, b1_2[ch], aty0, pm, np, aty1);
        #pragma unroll
        for (int d = 0; d < 8; d++) RT[(j0 + d) * 68 + scat] = aty1[d];   // Y1
        __syncthreads();   // (Y1 ready; Y0 reads done)

        // ---- P4: store o0; [p0: prefetch plane1 x]; prod1; a2y -> RX; a2x ----
        st8(&o0[maj * 64 + j0], prod0);
        if (p == 0) ld8(&xg1[maj * 64 + j0], xrN);   // HBM latency hides under P4/P5
        float prod1[8];
        {
            float y1r[8];
            ld8(&RT[rdb], y1r);
            #pragma unroll
            for (int j = 0; j < 8; j++) prod1[j] = a1x[j] * y1r[j];
        }
        {
            float a2y[8];
            sconv21(w2_2 + ch * 21, b2_2[ch], aty1, pm, pm2, np, np2, a2y);
            #pragma unroll
            for (int d = 0; d < 8; d++) RX[(j0 + d) * 68 + scat] = a2y[d]; // Y2
        }
        float a2x[8];
        sconv21(w2_1 + ch * 21, b2_1[ch], a1x, pm, pm2, np, np2, a2x);
        __syncthreads();   // (Y2 ready; Y1 reads done -> RT free)

        // ---- P5: store o1; prod2 = a2x*Y2row; store o2; [p0: commit plane1 x] ----
        st8(&o1[maj * 64 + j0], prod1);
        {
            float y2r[8], prod2[8];
            ld8(&RX[rdb], y2r);
            #pragma unroll
            for (int j = 0; j < 8; j++) prod2[j] = a2x[j] * y2r[j];
            st8(&o2[maj * 64 + j0], prod2);
        }
        if (p == 0) {
            commit_x(RT, xrN, t, maj, j0);   // plane1 X into freed RT
            __syncthreads();                 // plane1 B1 (also guards RX reuse)
        }
    }
}

extern "C" void kernel_launch(void* const* d_in, const int* in_sizes, int n_in,
                              void* d_out, int out_size, void* d_ws, size_t ws_size,
                              hipStream_t stream) {
    msca_fused<<<1024, 512, 0, stream>>>(
        (const float*)d_in[0],
        (const float*)d_in[1],  (const float*)d_in[2],
        (const float*)d_in[3],  (const float*)d_in[4],
        (const float*)d_in[5],  (const float*)d_in[6],
        (const float*)d_in[7],  (const float*)d_in[8],
        (const float*)d_in[9],  (const float*)d_in[10],
        (const float*)d_in[11], (const float*)d_in[12],
        (const float*)d_in[13], (const float*)d_in[14],
        (float*)d_out);
}

// Round 12
// 43.418 us; speedup vs baseline: 1.0566x; 1.0566x over previous
//
#include <hip/hip_runtime.h>

// MSCA fused multi-scale depthwise conv chain, one workgroup per (b,c) plane.
// x:[8,256,64,64] f32 -> (attn_0, attn_1, attn_2) each [8,256,64,64] f32.
//
// R11 = R9 components, 3-phase schedule (barriers 5 -> 3):
//  P1: attn = conv5x5(x) (rows from LDS X); scatter ATT_T.
//  P2: read T-strip; a0y->a1y->a2y REGISTER-CHAINED (no barriers between);
//      scatter Y0 (overlays X), Y1, Y2.
//  P3: issue all Y-row reads up front (6x b128, latency under compute);
//      a0x->a1x->a2x register chain; prod_i = a_ix * Y_i row; store o0/o1/o2.
//      No LDS writes in P3; no trailing barrier; stores never hit a drain.
// 512 thr, 8 px/thread, strips of 8, DPP halos hoisted+selected (R6 lesson),
// transpose involution swizzle (R7-proven):
//   scatter:  buf[(8*lane8+e)*68 + (maj ^ (lane8<<3))]
//   strip rd: buf[maj*68 + ((lane8 ^ ((maj>>3)&7))<<3) + e]   (2x b128)
// LDS: RX(4624: X -> Y0 after B2) + RT(4352: ATT_T) + RY1 + RY2 = 70720 B.

#define RX_W 4624                  // 68*68
#define RY_W 4352                  // 64*68
#define LDS_WORDS (RX_W + 3 * RY_W)   // 17680 words = 70720 B

__device__ __forceinline__ float dppsr1(float v) {   // lane i <- i-1 (16-lane rows)
    return __int_as_float(__builtin_amdgcn_update_dpp(
        0, __float_as_int(v), 0x111, 0xF, 0xF, false));
}
__device__ __forceinline__ float dppsr2(float v) {   // lane i <- i-2
    return __int_as_float(__builtin_amdgcn_update_dpp(
        0, __float_as_int(v), 0x112, 0xF, 0xF, false));
}
__device__ __forceinline__ float dppsl1(float v) {   // lane i <- i+1
    return __int_as_float(__builtin_amdgcn_update_dpp(
        0, __float_as_int(v), 0x101, 0xF, 0xF, false));
}
__device__ __forceinline__ float dppsl2(float v) {   // lane i <- i+2
    return __int_as_float(__builtin_amdgcn_update_dpp(
        0, __float_as_int(v), 0x102, 0xF, 0xF, false));
}
__device__ __forceinline__ void ld8(const float* p, float* d) {
    float4 a = *(const float4*)p, b = *(const float4*)(p + 4);
    d[0]=a.x; d[1]=a.y; d[2]=a.z; d[3]=a.w; d[4]=b.x; d[5]=b.y; d[6]=b.z; d[7]=b.w;
}
__device__ __forceinline__ void st8(float* p, const float* d) {
    float4 a, b;
    a.x=d[0]; a.y=d[1]; a.z=d[2]; a.w=d[3]; b.x=d[4]; b.y=d[5]; b.z=d[6]; b.w=d[7];
    *(float4*)p = a; *(float4*)(p + 4) = b;
}

// Accumulate window part: src[i] at window position W0+i (N elems), static idx.
template<int K, int W0, int N>
__device__ __forceinline__ void cpart(const float* __restrict__ wt,
                                      const float* s, float* acc) {
    #pragma unroll
    for (int v = 0; v < K; v++) {
        #pragma unroll
        for (int j = 0; j < 8; j++) {
            const int p = j + v - W0;
            if (p >= 0 && p < N) acc[j] += wt[v] * s[p];
        }
    }
}

// Strip conv, K=2H+1 taps, H<=8: halo from lane+-1 (DPP hoisted, select after).
template<int H>
__device__ __forceinline__ void sconv(const float* __restrict__ wt, float bb,
                                      const float* a, bool pm, bool np, float* acc) {
    constexpr int K = 2 * H + 1;
    float pv[H], nv[H];
    #pragma unroll
    for (int i = 0; i < H; i++) pv[i] = dppsr1(a[8 - H + i]);
    #pragma unroll
    for (int i = 0; i < H; i++) nv[i] = dppsl1(a[i]);
    #pragma unroll
    for (int i = 0; i < H; i++) pv[i] = pm ? pv[i] : 0.f;
    #pragma unroll
    for (int i = 0; i < H; i++) nv[i] = np ? nv[i] : 0.f;
    #pragma unroll
    for (int j = 0; j < 8; j++) acc[j] = bb;
    cpart<K, 0, H>(wt, pv, acc);
    cpart<K, H, 8>(wt, a, acc);
    cpart<K, H + 8, H>(wt, nv, acc);
}

// 21-tap strip conv (H=10): halo spans lane+-1 (8) and lane+-2 (2).
__device__ __forceinline__ void sconv21(const float* __restrict__ wt, float bb,
                                        const float* a, bool pm, bool pm2,
                                        bool np, bool np2, float* acc) {
    #pragma unroll
    for (int j = 0; j < 8; j++) acc[j] = bb;
    {
        float q[2];
        q[0] = dppsr2(a[6]); q[1] = dppsr2(a[7]);
        q[0] = pm2 ? q[0] : 0.f; q[1] = pm2 ? q[1] : 0.f;
        cpart<21, 0, 2>(wt, q, acc);
    }
    {
        float pv[8];
        #pragma unroll
        for (int i = 0; i < 8; i++) pv[i] = dppsr1(a[i]);
        #pragma unroll
        for (int i = 0; i < 8; i++) pv[i] = pm ? pv[i] : 0.f;
        cpart<21, 2, 8>(wt, pv, acc);
    }
    cpart<21, 10, 8>(wt, a, acc);
    {
        float nv[8];
        #pragma unroll
        for (int i = 0; i < 8; i++) nv[i] = dppsl1(a[i]);
        #pragma unroll
        for (int i = 0; i < 8; i++) nv[i] = np ? nv[i] : 0.f;
        cpart<21, 18, 8>(wt, nv, acc);
    }
    {
        float q[2];
        q[0] = dppsl2(a[0]); q[1] = dppsl2(a[1]);
        q[0] = np2 ? q[0] : 0.f; q[1] = np2 ? q[1] : 0.f;
        cpart<21, 26, 2>(wt, q, acc);
    }
}

__global__ __launch_bounds__(512, 4)
void msca_fused(const float* __restrict__ x,
                const float* __restrict__ w0,   const float* __restrict__ b0,
                const float* __restrict__ w0_1, const float* __restrict__ b0_1,
                const float* __restrict__ w0_2, const float* __restrict__ b0_2,
                const float* __restrict__ w1_1, const float* __restrict__ b1_1,
                const float* __restrict__ w1_2, const float* __restrict__ b1_2,
                const float* __restrict__ w2_1, const float* __restrict__ b2_1,
                const float* __restrict__ w2_2, const float* __restrict__ b2_2,
                float* __restrict__ out)
{
    __shared__ __align__(16) float lds[LDS_WORDS];
    float* RX  = lds;                       // X -> Y0 (after B2)
    float* RT  = lds + RX_W;                // ATT_T
    float* RY1 = lds + RX_W + RY_W;         // Y1
    float* RY2 = lds + RX_W + 2 * RY_W;     // Y2

    const int t     = threadIdx.x;     // 0..511
    const int maj   = t >> 3;          // X: image row ; T: image col
    const int lane8 = t & 7;
    const int j0    = lane8 << 3;

    const bool pm  = lane8 >= 1, np  = lane8 <= 6;
    const bool pm2 = lane8 >= 2, np2 = lane8 <= 5;

    const int scat = maj ^ (lane8 << 3);                           // scatter minor
    const int rdb  = maj * 68 + ((lane8 ^ ((maj >> 3) & 7)) << 3); // strip read base

    const int plane = blockIdx.x;
    const int ch    = plane & 255;

    const float* xg = x + (size_t)plane * 4096;
    float* o0 = out + (size_t)plane * 4096;
    float* o1 = o0 + 8388608;
    float* o2 = o1 + 8388608;

    // ---- stage 0: load x (8 px), zero X halos, commit ----
    float xr[8];
    ld8(&xg[maj * 64 + j0], xr);
    if (t < 136) { RX[t] = 0.f; RX[t + 4488] = 0.f; }        // halo rows 0,1,66,67
    if (t < 256) {                                            // side cols rows 2..65
        int rr = 2 + (t >> 2), cc = t & 3;
        RX[rr * 68 + (cc < 2 ? cc : cc + 64)] = 0.f;
    }
    {
        float* row = &RX[(maj + 2) * 68 + j0 + 2];
        float2 p;
        p.x = xr[0]; p.y = xr[1]; ((float2*)row)[0] = p;
        p.x = xr[2]; p.y = xr[3]; ((float2*)row)[1] = p;
        p.x = xr[4]; p.y = xr[5]; ((float2*)row)[2] = p;
        p.x = xr[6]; p.y = xr[7]; ((float2*)row)[3] = p;
    }
    __syncthreads();   // B1 (X ready)

    // ---- P1: attn = conv5x5(x)+b0 (rows from RX); scatter ATT_T ----
    float attn[8];
    {
        const float bb = b0[ch];
        #pragma unroll
        for (int j = 0; j < 8; j++) attn[j] = bb;
        const float* w0p = w0 + ch * 25;
        #pragma unroll
        for (int dr = 0; dr < 5; dr++) {
            float wnd[12];                      // image cols j0-2 .. j0+9
            const float* rowp = &RX[(maj + dr) * 68 + j0];
            float4 qa = *(const float4*)rowp;
            float4 qb = *(const float4*)(rowp + 4);
            float4 qc = *(const float4*)(rowp + 8);
            wnd[0]=qa.x; wnd[1]=qa.y; wnd[2]=qa.z;  wnd[3]=qa.w;
            wnd[4]=qb.x; wnd[5]=qb.y; wnd[6]=qb.z;  wnd[7]=qb.w;
            wnd[8]=qc.x; wnd[9]=qc.y; wnd[10]=qc.z; wnd[11]=qc.w;
            #pragma unroll
            for (int v = 0; v < 5; v++) {
                const float ww = w0p[dr * 5 + v];
                #pragma unroll
                for (int j = 0; j < 8; j++) attn[j] += ww * wnd[j + v];
            }
        }
        #pragma unroll
        for (int e = 0; e < 8; e++) RT[(j0 + e) * 68 + scat] = attn[e];
    }
    __syncthreads();   // B2 (ATT_T ready; X reads done -> RX free for Y0)

    // ---- P2: read T-strip; a0y -> a1y -> a2y register chain; scatter Y0/Y1/Y2 ----
    {
        float stv[8];
        ld8(&RT[rdb], stv);
        float a0y[8];
        sconv<3>(w0_2 + ch * 7, b0_2[ch], stv, pm, np, a0y);
        #pragma unroll
        for (int d = 0; d < 8; d++) RX[(j0 + d) * 68 + scat] = a0y[d];    // Y0
        float a1y[8];
        sconv<5>(w1_2 + ch * 11, b1_2[ch], a0y, pm, np, a1y);
        #pragma unroll
        for (int d = 0; d < 8; d++) RY1[(j0 + d) * 68 + scat] = a1y[d];   // Y1
        float a2y[8];
        sconv21(w2_2 + ch * 21, b2_2[ch], a1y, pm, pm2, np, np2, a2y);
        #pragma unroll
        for (int d = 0; d < 8; d++) RY2[(j0 + d) * 68 + scat] = a2y[d];   // Y2
    }
    __syncthreads();   // B3 (Y0/Y1/Y2 ready)

    // ---- P3: issue Y-row reads early; x-chain; products; stores ----
    {
        float y0r[8], y1r[8], y2r[8];
        ld8(&RX[rdb],  y0r);       // 6x b128 in flight; latency hides
        ld8(&RY1[rdb], y1r);       // under the a0x/a1x/a2x compute below
        ld8(&RY2[rdb], y2r);

        float a0x[8];
        sconv<3>(w0_1 + ch * 7, b0_1[ch], attn, pm, np, a0x);
        float prod0[8];
        #pragma unroll
        for (int j = 0; j < 8; j++) prod0[j] = a0x[j] * y0r[j];
        st8(&o0[maj * 64 + j0], prod0);

        float a1x[8];
        sconv<5>(w1_1 + ch * 11, b1_1[ch], a0x, pm, np, a1x);
        float prod1[8];
        #pragma unroll
        for (int j = 0; j < 8; j++) prod1[j] = a1x[j] * y1r[j];
        st8(&o1[maj * 64 + j0], prod1);

        float a2x[8];
        sconv21(w2_1 + ch * 21, b2_1[ch], a1x, pm, pm2, np, np2, a2x);
        float prod2[8];
        #pragma unroll
        for (int j = 0; j < 8; j++) prod2[j] = a2x[j] * y2r[j];
        st8(&o2[maj * 64 + j0], prod2);
    }
}

extern "C" void kernel_launch(void* const* d_in, const int* in_sizes, int n_in,
                              void* d_out, int out_size, void* d_ws, size_t ws_size,
                              hipStream_t stream) {
    msca_fused<<<2048, 512, 0, stream>>>(
        (const float*)d_in[0],
        (const float*)d_in[1],  (const float*)d_in[2],
        (const float*)d_in[3],  (const float*)d_in[4],
        (const float*)d_in[5],  (const float*)d_in[6],
        (const float*)d_in[7],  (const float*)d_in[8],
        (const float*)d_in[9],  (const float*)d_in[10],
        (const float*)d_in[11], (const float*)d_in[12],
        (const float*)d_in[13], (const float*)d_in[14],
        (float*)d_out);
}